// Round 1
// baseline (8171.371 us; speedup 1.0000x reference)
//
#include <hip/hip_runtime.h>
#include <hip/hip_fp16.h>

// ---- problem constants ----
#define Bb 8
#define Ll 4106
#define Cc 768
#define VPT_ 10
#define WSz 14
#define NWIN 25
#define BW_ 200
#define LW_ 206
#define NHh 12
#define HDd 64

typedef _Float16 half8 __attribute__((ext_vector_type(8)));
typedef float floatx4 __attribute__((ext_vector_type(4)));

// ---------------- fp32 -> fp16 convert ----------------
__global__ void f2h_kernel(const float* __restrict__ in, _Float16* __restrict__ out, int n) {
    int i = blockIdx.x * 256 + threadIdx.x;
    if (i < n) out[i] = (_Float16)in[i];
}

// ---------------- LN1 + window scatter ----------------
// One block per (b,l) row. Prompt rows (l<10) broadcast to 25 windows at rows (w*8+b);
// spatial rows go to window (b*25 + ih*5 + iw), slot 10 + ii*14 + jj. Padded slots stay 0 (memset).
__global__ __launch_bounds__(256) void ln1_scatter_kernel(
    const float* __restrict__ x, const float* __restrict__ w, const float* __restrict__ bia,
    _Float16* __restrict__ tok)
{
    int r = blockIdx.x;
    int b = r / Ll, l = r % Ll;
    const float* xr = x + (size_t)r * Cc;
    int t = threadIdx.x;
    float v0 = xr[t], v1 = xr[t + 256], v2 = xr[t + 512];
    float s1 = v0 + v1 + v2;
    float s2 = v0 * v0 + v1 * v1 + v2 * v2;
    #pragma unroll
    for (int off = 32; off > 0; off >>= 1) {
        s1 += __shfl_down(s1, off);
        s2 += __shfl_down(s2, off);
    }
    __shared__ float red[8];
    int wv = t >> 6, ln = t & 63;
    if (ln == 0) { red[wv] = s1; red[4 + wv] = s2; }
    __syncthreads();
    float fs1 = red[0] + red[1] + red[2] + red[3];
    float fs2 = red[4] + red[5] + red[6] + red[7];
    float mean = fs1 * (1.0f / Cc);
    float var  = fs2 * (1.0f / Cc) - mean * mean;
    float rstd = rsqrtf(var + 1e-5f);
    float vv[3] = {v0, v1, v2};
    if (l < VPT_) {
        #pragma unroll
        for (int i = 0; i < 3; ++i) {
            int c = t + i * 256;
            _Float16 hy = (_Float16)((vv[i] - mean) * rstd * w[c] + bia[c]);
            for (int wi = 0; wi < NWIN; ++wi)
                tok[((size_t)(wi * Bb + b) * LW_ + l) * Cc + c] = hy;
        }
    } else {
        int sidx = l - VPT_;
        int ii = sidx >> 6, jj = sidx & 63;
        size_t drow = (size_t)(b * NWIN + (ii / WSz) * 5 + (jj / WSz)) * LW_
                      + VPT_ + (ii % WSz) * WSz + (jj % WSz);
        #pragma unroll
        for (int i = 0; i < 3; ++i) {
            int c = t + i * 256;
            tok[drow * Cc + c] = (_Float16)((vv[i] - mean) * rstd * w[c] + bia[c]);
        }
    }
}

// ---------------- LN2 (plain) ----------------
__global__ __launch_bounds__(256) void ln2_kernel(
    const float* __restrict__ x2, const float* __restrict__ w, const float* __restrict__ bia,
    _Float16* __restrict__ xn)
{
    int r = blockIdx.x;
    const float* xr = x2 + (size_t)r * Cc;
    int t = threadIdx.x;
    float v0 = xr[t], v1 = xr[t + 256], v2 = xr[t + 512];
    float s1 = v0 + v1 + v2;
    float s2 = v0 * v0 + v1 * v1 + v2 * v2;
    #pragma unroll
    for (int off = 32; off > 0; off >>= 1) {
        s1 += __shfl_down(s1, off);
        s2 += __shfl_down(s2, off);
    }
    __shared__ float red[8];
    int wv = t >> 6, ln = t & 63;
    if (ln == 0) { red[wv] = s1; red[4 + wv] = s2; }
    __syncthreads();
    float fs1 = red[0] + red[1] + red[2] + red[3];
    float fs2 = red[4] + red[5] + red[6] + red[7];
    float mean = fs1 * (1.0f / Cc);
    float var  = fs2 * (1.0f / Cc) - mean * mean;
    float rstd = rsqrtf(var + 1e-5f);
    float vv[3] = {v0, v1, v2};
    #pragma unroll
    for (int i = 0; i < 3; ++i) {
        int c = t + i * 256;
        xn[(size_t)r * Cc + c] = (_Float16)((vv[i] - mean) * rstd * w[c] + bia[c]);
    }
}

// ---------------- MFMA fp16 GEMM: C[M,N] = A[M,K] @ W[N,K]^T + bias ----------------
// EPI 0: -> fp16 out. EPI 1: gelu -> fp16 out. EPI 2: + addsrc -> fp32 out.
// 64x64 tile, BK=32, 256 thr = 4 waves, wave w does rows [16w,16w+16) x all 64 cols.
// LDS rows padded 32->40 halves (80B) to spread banks for ds_read_b128.
template <int EPI>
__global__ __launch_bounds__(256) void gemm_f16(
    const _Float16* __restrict__ A, const _Float16* __restrict__ W,
    const float* __restrict__ bias, const float* __restrict__ addsrc,
    _Float16* __restrict__ outH, float* __restrict__ outF,
    int M, int N, int K)
{
    __shared__ alignas(16) _Float16 As[64 * 40];
    __shared__ alignas(16) _Float16 Bs[64 * 40];
    int tid = threadIdx.x;
    int row0 = blockIdx.x * 64, col0 = blockIdx.y * 64;
    int wv = tid >> 6, ln = tid & 63;
    int m16 = ln & 15, quad = ln >> 4;
    int sr = tid >> 2, sc = (tid & 3) * 8;

    floatx4 acc[4] = {};

    const _Float16* Ap = A + (size_t)(row0 + sr) * K + sc;
    const _Float16* Wp = W + (size_t)(col0 + sr) * K + sc;
    bool aok = (row0 + sr) < M;

    for (int k0 = 0; k0 < K; k0 += 32) {
        uint4 av = make_uint4(0u, 0u, 0u, 0u);
        if (aok) av = *reinterpret_cast<const uint4*>(Ap + k0);
        uint4 wvv = *reinterpret_cast<const uint4*>(Wp + k0);
        __syncthreads();
        *reinterpret_cast<uint4*>(&As[sr * 40 + sc]) = av;
        *reinterpret_cast<uint4*>(&Bs[sr * 40 + sc]) = wvv;
        __syncthreads();
        half8 af = *reinterpret_cast<const half8*>(&As[(wv * 16 + m16) * 40 + quad * 8]);
        #pragma unroll
        for (int nt = 0; nt < 4; ++nt) {
            half8 bf = *reinterpret_cast<const half8*>(&Bs[(nt * 16 + m16) * 40 + quad * 8]);
            acc[nt] = __builtin_amdgcn_mfma_f32_16x16x32_f16(af, bf, acc[nt], 0, 0, 0);
        }
    }
    #pragma unroll
    for (int nt = 0; nt < 4; ++nt) {
        int col = col0 + nt * 16 + m16;
        float bv = bias[col];
        #pragma unroll
        for (int rr = 0; rr < 4; ++rr) {
            int row = row0 + wv * 16 + quad * 4 + rr;
            if (row < M) {
                float v = acc[nt][rr] + bv;
                if (EPI == 0) {
                    outH[(size_t)row * N + col] = (_Float16)v;
                } else if (EPI == 1) {
                    v = 0.5f * v * (1.0f + erff(v * 0.70710678118654752f));
                    outH[(size_t)row * N + col] = (_Float16)v;
                } else {
                    outF[(size_t)row * N + col] = v + addsrc[(size_t)row * N + col];
                }
            }
        }
    }
}

// ---------------- attention (one block per (window, head)) ----------------
// qkv fp16 (200*206, 2304): q at col h*64, k at 768+h*64, v at 1536+h*64.
// k,v staged in LDS (row stride 66 halves to kill bank conflicts).
// One wave per query row (4 rows in flight). Decomposed rel-pos: lanes 0..13 hold
// rh[kh]=dot(q,Rh[qh-kh+13]), lanes 14..27 hold rw[kw]; broadcast via shfl.
__global__ __launch_bounds__(256) void attn_kernel(
    const _Float16* __restrict__ qkv,
    const float* __restrict__ relh, const float* __restrict__ relw,
    _Float16* __restrict__ attout)
{
    int bw = blockIdx.x / NHh;
    int hh = blockIdx.x % NHh;
    __shared__ alignas(16) _Float16 kl[LW_ * 66];
    __shared__ alignas(16) _Float16 vl[LW_ * 66];
    int tid = threadIdx.x;
    const _Float16* base = qkv + (size_t)bw * LW_ * 2304 + hh * HDd;
    for (int idx = tid; idx < LW_ * 64; idx += 256) {
        int t = idx >> 6, d = idx & 63;
        const _Float16* src = base + (size_t)t * 2304;
        kl[t * 66 + d] = src[768 + d];
        vl[t * 66 + d] = src[1536 + d];
    }
    __syncthreads();
    const unsigned int* kl32 = reinterpret_cast<const unsigned int*>(kl);
    int wv = tid >> 6, ln = tid & 63;
    for (int qr = wv; qr < LW_; qr += 4) {
        float qreg = (float)base[(size_t)qr * 2304 + ln];  // q[d=lane], unscaled
        float rel = 0.0f;
        if (qr >= VPT_) {
            int q2 = qr - VPT_;
            int qh = q2 / WSz, qw = q2 % WSz;
            int i = (ln < 14) ? ln : ((ln < 28) ? ln - 14 : 0);
            const float* rp = (ln < 14) ? (relh + (qh - i + 13) * 64)
                                        : (relw + (qw - i + 13) * 64);
            float a = 0.0f;
            for (int d = 0; d < 64; ++d) {
                float qd = __shfl(qreg, d);
                a += qd * rp[d];
            }
            rel = a;  // valid in lanes 0..27
        }
        // scores for keys lane, lane+64, lane+128, lane+192
        float a[4] = {0.f, 0.f, 0.f, 0.f};
        int kidx[4];
        #pragma unroll
        for (int j = 0; j < 4; ++j) { int key = ln + j * 64; kidx[j] = (key < LW_) ? key : (LW_ - 1); }
        for (int dp = 0; dp < 32; ++dp) {
            float q0 = __shfl(qreg, 2 * dp);
            float q1 = __shfl(qreg, 2 * dp + 1);
            #pragma unroll
            for (int j = 0; j < 4; ++j) {
                unsigned int u = kl32[kidx[j] * 33 + dp];
                _Float16 h0 = __builtin_bit_cast(_Float16, (unsigned short)(u & 0xffffu));
                _Float16 h1 = __builtin_bit_cast(_Float16, (unsigned short)(u >> 16));
                a[j] += q0 * (float)h0 + q1 * (float)h1;
            }
        }
        float scr[4];
        #pragma unroll
        for (int j = 0; j < 4; ++j) {
            int key = ln + j * 64;
            int k2 = key - VPT_; if (k2 < 0) k2 = 0;
            int kh = k2 / WSz, kw = k2 % WSz;      // kh<=17<64: safe shfl src
            float rh_b = __shfl(rel, kh);          // non-divergent shfl
            float rw_b = __shfl(rel, 14 + kw);
            float s = a[j] * 0.125f;               // SCALE on qk only, not rel
            if (qr >= VPT_ && key >= VPT_) s += rh_b + rw_b;
            scr[j] = (key < LW_) ? s : -1e30f;
        }
        float mx = fmaxf(fmaxf(scr[0], scr[1]), fmaxf(scr[2], scr[3]));
        #pragma unroll
        for (int off = 32; off > 0; off >>= 1) mx = fmaxf(mx, __shfl_xor(mx, off));
        float p[4]; float lsum = 0.0f;
        #pragma unroll
        for (int j = 0; j < 4; ++j) { p[j] = __expf(scr[j] - mx); lsum += p[j]; }
        #pragma unroll
        for (int off = 32; off > 0; off >>= 1) lsum += __shfl_xor(lsum, off);
        float inv = 1.0f / lsum;
        #pragma unroll
        for (int j = 0; j < 4; ++j) p[j] *= inv;
        float o = 0.0f;
        #pragma unroll
        for (int j = 0; j < 4; ++j) {
            int lim = LW_ - j * 64; if (lim > 64) lim = 64;
            for (int kk = 0; kk < lim; ++kk) {
                float pk = __shfl(p[j], kk);
                o += pk * (float)vl[(j * 64 + kk) * 66 + ln];
            }
        }
        attout[((size_t)bw * LW_ + qr) * Cc + hh * HDd + ln] = (_Float16)o;
    }
}

// ---------------- x2 = x + window-reverse(proj); prompt = mean over 25 windows ----------------
__global__ __launch_bounds__(256) void build_x2_kernel(
    const float* __restrict__ x, const _Float16* __restrict__ proj, float* __restrict__ x2)
{
    int r = blockIdx.x;
    int b = r / Ll, l = r % Ll;
    int t = threadIdx.x;
    size_t srow = 0;
    bool prompt = (l < VPT_);
    if (!prompt) {
        int sidx = l - VPT_;
        int ii = sidx >> 6, jj = sidx & 63;
        srow = (size_t)(b * NWIN + (ii / WSz) * 5 + (jj / WSz)) * LW_
               + VPT_ + (ii % WSz) * WSz + (jj % WSz);
    }
    #pragma unroll
    for (int i = 0; i < 3; ++i) {
        int c = t + i * 256;
        float v;
        if (prompt) {
            float s = 0.0f;
            for (int wi = 0; wi < NWIN; ++wi)
                s += (float)proj[((size_t)(wi * Bb + b) * LW_ + l) * Cc + c];
            v = s * (1.0f / NWIN);
        } else {
            v = (float)proj[srow * Cc + c];
        }
        size_t off = (size_t)r * Cc + c;
        x2[off] = x[off] + v;
    }
}

// ---------------- launcher ----------------
extern "C" void kernel_launch(void* const* d_in, const int* in_sizes, int n_in,
                              void* d_out, int out_size, void* d_ws, size_t ws_size,
                              hipStream_t stream)
{
    const float* x     = (const float*)d_in[0];
    const float* ln1w  = (const float*)d_in[1];
    const float* ln1b  = (const float*)d_in[2];
    const float* qkvw  = (const float*)d_in[3];
    const float* qkvb  = (const float*)d_in[4];
    const float* projw = (const float*)d_in[5];
    const float* projb = (const float*)d_in[6];
    const float* relh  = (const float*)d_in[7];
    const float* relw  = (const float*)d_in[8];
    const float* ln2w  = (const float*)d_in[9];
    const float* ln2b  = (const float*)d_in[10];
    const float* w1    = (const float*)d_in[11];
    const float* b1    = (const float*)d_in[12];
    const float* w2    = (const float*)d_in[13];
    const float* b2    = (const float*)d_in[14];
    float* out = (float*)d_out;
    char* ws = (char*)d_ws;

    // workspace layout (bytes, all 256-aligned); peak ~267 MB
    _Float16* wqkv_h  = (_Float16*)(ws + 0);          // 2304*768*2   = 3,538,944
    _Float16* wproj_h = (_Float16*)(ws + 3538944);    //  768*768*2   = 1,179,648
    _Float16* w1_h    = (_Float16*)(ws + 4718592);    // 3072*768*2   = 4,718,592
    _Float16* w2_h    = (_Float16*)(ws + 9437184);    //  768*3072*2  = 4,718,592
    _Float16* tokA    = (_Float16*)(ws + 14155776);   // region A: 41200*768*2 = 63,283,200
    char* regB = ws + 77438976;
    _Float16* qkv_h  = (_Float16*)regB;               // 41200*2304*2 = 189,849,600
    _Float16* proj_h = (_Float16*)regB;               // reuse after qkv dead (63,283,200)
    float*    x2buf  = (float*)(regB + 63283200);     // 32848*768*4  = 100,927,488
    _Float16* hbuf   = (_Float16*)regB;               // reuse after proj dead (8212*3072*2)

    // 1. weights -> fp16
    f2h_kernel<<<(2304 * 768 + 255) / 256, 256, 0, stream>>>(qkvw, wqkv_h, 2304 * 768);
    f2h_kernel<<<(768 * 768 + 255) / 256, 256, 0, stream>>>(projw, wproj_h, 768 * 768);
    f2h_kernel<<<(3072 * 768 + 255) / 256, 256, 0, stream>>>(w1, w1_h, 3072 * 768);
    f2h_kernel<<<(768 * 3072 + 255) / 256, 256, 0, stream>>>(w2, w2_h, 768 * 3072);
    // 2. zero tok (padded window slots must be 0)
    hipMemsetAsync(tokA, 0, (size_t)41200 * 768 * 2, stream);
    // 3. LN1 + scatter into windows
    ln1_scatter_kernel<<<Bb * Ll, 256, 0, stream>>>(x, ln1w, ln1b, tokA);
    // 4. QKV gemm (M=41200, N=2304, K=768)
    gemm_f16<0><<<dim3(644, 36), 256, 0, stream>>>(tokA, wqkv_h, qkvb, nullptr, qkv_h, nullptr, 41200, 2304, 768);
    // 5. attention -> attout (reuses region A)
    attn_kernel<<<BW_ * NHh, 256, 0, stream>>>(qkv_h, relh, relw, tokA);
    // 6. proj gemm (M=41200, N=768, K=768)
    gemm_f16<0><<<dim3(644, 12), 256, 0, stream>>>(tokA, wproj_h, projb, nullptr, proj_h, nullptr, 41200, 768, 768);
    // 7. x2 = x + window-reverse / prompt-mean
    build_x2_kernel<<<Bb * Ll, 256, 0, stream>>>(x, proj_h, x2buf);
    // 8. LN2 -> xn2 (region A)
    ln2_kernel<<<Bb * Ll, 256, 0, stream>>>(x2buf, ln2w, ln2b, tokA);
    // 9. MLP in 4 chunks of 8212 rows (h buffer reuses proj slot)
    for (int ch = 0; ch < 4; ++ch) {
        size_t r0 = (size_t)ch * 8212;
        gemm_f16<1><<<dim3(129, 48), 256, 0, stream>>>(tokA + r0 * 768, w1_h, b1, nullptr, hbuf, nullptr, 8212, 3072, 768);
        gemm_f16<2><<<dim3(129, 12), 256, 0, stream>>>(hbuf, w2_h, b2, x2buf + r0 * 768, nullptr, out + r0 * 768, 8212, 768, 3072);
    }
}

// Round 2
// 2115.454 us; speedup vs baseline: 3.8627x; 3.8627x over previous
//
#include <hip/hip_runtime.h>
#include <hip/hip_fp16.h>

// ---- problem constants ----
#define Bb 8
#define Ll 4106
#define Cc 768
#define VPT_ 10
#define WSz 14
#define NWIN 25
#define BW_ 200
#define LW_ 206
#define NHh 12
#define HDd 64

typedef _Float16 half8 __attribute__((ext_vector_type(8)));
typedef float floatx4 __attribute__((ext_vector_type(4)));

// ---------------- fp32 -> fp16 convert ----------------
__global__ void f2h_kernel(const float* __restrict__ in, _Float16* __restrict__ out, int n) {
    int i = blockIdx.x * 256 + threadIdx.x;
    if (i < n) out[i] = (_Float16)in[i];
}

// ---------------- LN1 + window scatter ----------------
__global__ __launch_bounds__(256) void ln1_scatter_kernel(
    const float* __restrict__ x, const float* __restrict__ w, const float* __restrict__ bia,
    _Float16* __restrict__ tok)
{
    int r = blockIdx.x;
    int b = r / Ll, l = r % Ll;
    const float* xr = x + (size_t)r * Cc;
    int t = threadIdx.x;
    float v0 = xr[t], v1 = xr[t + 256], v2 = xr[t + 512];
    float s1 = v0 + v1 + v2;
    float s2 = v0 * v0 + v1 * v1 + v2 * v2;
    #pragma unroll
    for (int off = 32; off > 0; off >>= 1) {
        s1 += __shfl_down(s1, off);
        s2 += __shfl_down(s2, off);
    }
    __shared__ float red[8];
    int wv = t >> 6, ln = t & 63;
    if (ln == 0) { red[wv] = s1; red[4 + wv] = s2; }
    __syncthreads();
    float fs1 = red[0] + red[1] + red[2] + red[3];
    float fs2 = red[4] + red[5] + red[6] + red[7];
    float mean = fs1 * (1.0f / Cc);
    float var  = fs2 * (1.0f / Cc) - mean * mean;
    float rstd = rsqrtf(var + 1e-5f);
    float vv[3] = {v0, v1, v2};
    if (l < VPT_) {
        #pragma unroll
        for (int i = 0; i < 3; ++i) {
            int c = t + i * 256;
            _Float16 hy = (_Float16)((vv[i] - mean) * rstd * w[c] + bia[c]);
            for (int wi = 0; wi < NWIN; ++wi)
                tok[((size_t)(wi * Bb + b) * LW_ + l) * Cc + c] = hy;
        }
    } else {
        int sidx = l - VPT_;
        int ii = sidx >> 6, jj = sidx & 63;
        size_t drow = (size_t)(b * NWIN + (ii / WSz) * 5 + (jj / WSz)) * LW_
                      + VPT_ + (ii % WSz) * WSz + (jj % WSz);
        #pragma unroll
        for (int i = 0; i < 3; ++i) {
            int c = t + i * 256;
            tok[drow * Cc + c] = (_Float16)((vv[i] - mean) * rstd * w[c] + bia[c]);
        }
    }
}

// ---------------- LN2 (plain) ----------------
__global__ __launch_bounds__(256) void ln2_kernel(
    const float* __restrict__ x2, const float* __restrict__ w, const float* __restrict__ bia,
    _Float16* __restrict__ xn)
{
    int r = blockIdx.x;
    const float* xr = x2 + (size_t)r * Cc;
    int t = threadIdx.x;
    float v0 = xr[t], v1 = xr[t + 256], v2 = xr[t + 512];
    float s1 = v0 + v1 + v2;
    float s2 = v0 * v0 + v1 * v1 + v2 * v2;
    #pragma unroll
    for (int off = 32; off > 0; off >>= 1) {
        s1 += __shfl_down(s1, off);
        s2 += __shfl_down(s2, off);
    }
    __shared__ float red[8];
    int wv = t >> 6, ln = t & 63;
    if (ln == 0) { red[wv] = s1; red[4 + wv] = s2; }
    __syncthreads();
    float fs1 = red[0] + red[1] + red[2] + red[3];
    float fs2 = red[4] + red[5] + red[6] + red[7];
    float mean = fs1 * (1.0f / Cc);
    float var  = fs2 * (1.0f / Cc) - mean * mean;
    float rstd = rsqrtf(var + 1e-5f);
    float vv[3] = {v0, v1, v2};
    #pragma unroll
    for (int i = 0; i < 3; ++i) {
        int c = t + i * 256;
        xn[(size_t)r * Cc + c] = (_Float16)((vv[i] - mean) * rstd * w[c] + bia[c]);
    }
}

// ---------------- MFMA fp16 GEMM: C[M,N] = A[M,K] @ W[N,K]^T + bias ----------------
template <int EPI>
__global__ __launch_bounds__(256) void gemm_f16(
    const _Float16* __restrict__ A, const _Float16* __restrict__ W,
    const float* __restrict__ bias, const float* __restrict__ addsrc,
    _Float16* __restrict__ outH, float* __restrict__ outF,
    int M, int N, int K)
{
    __shared__ alignas(16) _Float16 As[64 * 40];
    __shared__ alignas(16) _Float16 Bs[64 * 40];
    int tid = threadIdx.x;
    int row0 = blockIdx.x * 64, col0 = blockIdx.y * 64;
    int wv = tid >> 6, ln = tid & 63;
    int m16 = ln & 15, quad = ln >> 4;
    int sr = tid >> 2, sc = (tid & 3) * 8;

    floatx4 acc[4] = {};

    const _Float16* Ap = A + (size_t)(row0 + sr) * K + sc;
    const _Float16* Wp = W + (size_t)(col0 + sr) * K + sc;
    bool aok = (row0 + sr) < M;

    for (int k0 = 0; k0 < K; k0 += 32) {
        uint4 av = make_uint4(0u, 0u, 0u, 0u);
        if (aok) av = *reinterpret_cast<const uint4*>(Ap + k0);
        uint4 wvv = *reinterpret_cast<const uint4*>(Wp + k0);
        __syncthreads();
        *reinterpret_cast<uint4*>(&As[sr * 40 + sc]) = av;
        *reinterpret_cast<uint4*>(&Bs[sr * 40 + sc]) = wvv;
        __syncthreads();
        half8 af = *reinterpret_cast<const half8*>(&As[(wv * 16 + m16) * 40 + quad * 8]);
        #pragma unroll
        for (int nt = 0; nt < 4; ++nt) {
            half8 bf = *reinterpret_cast<const half8*>(&Bs[(nt * 16 + m16) * 40 + quad * 8]);
            acc[nt] = __builtin_amdgcn_mfma_f32_16x16x32_f16(af, bf, acc[nt], 0, 0, 0);
        }
    }
    #pragma unroll
    for (int nt = 0; nt < 4; ++nt) {
        int col = col0 + nt * 16 + m16;
        float bv = bias[col];
        #pragma unroll
        for (int rr = 0; rr < 4; ++rr) {
            int row = row0 + wv * 16 + quad * 4 + rr;
            if (row < M) {
                float v = acc[nt][rr] + bv;
                if (EPI == 0) {
                    outH[(size_t)row * N + col] = (_Float16)v;
                } else if (EPI == 1) {
                    v = 0.5f * v * (1.0f + erff(v * 0.70710678118654752f));
                    outH[(size_t)row * N + col] = (_Float16)v;
                } else {
                    outF[(size_t)row * N + col] = v + addsrc[(size_t)row * N + col];
                }
            }
        }
    }
}

// ---------------- MFMA attention: one block per (window, head), 4 waves ----------------
// LDS: K[206][64] stride 72 (S B-frags), V^T[64][224] stride 232 (PV B-frags),
// per-wave P chunk [16][32] stride 40 (C-layout -> A-layout round trip).
// rel-pos via two tiny MFMA GEMMs T_h/T_w = Q @ R^T, fetched into S C-layout by
// intra-quad shuffles (row of T for (quad,rr) lives in lanes quad*16+0..15, reg rr).
__global__ __launch_bounds__(256, 2) void attn_mfma_kernel(
    const _Float16* __restrict__ qkv,
    const float* __restrict__ relh, const float* __restrict__ relw,
    _Float16* __restrict__ attout)
{
    __shared__ alignas(16) _Float16 Ks[208 * 72];      // 29952 B
    __shared__ alignas(16) _Float16 Vt[64 * 232];      // 29696 B
    __shared__ alignas(16) _Float16 Pc[4][16 * 40];    //  5120 B  (total 64768 <= 64K)
    const int bwi = blockIdx.x / NHh, hh = blockIdx.x % NHh;
    const int tid = threadIdx.x;
    const _Float16* base = qkv + (size_t)bwi * LW_ * 2304 + hh * HDd;

    // stage K (vectorized 16B)
    for (int idx = tid; idx < LW_ * 8; idx += 256) {
        int row = idx >> 3, c8 = idx & 7;
        *reinterpret_cast<uint4*>(&Ks[row * 72 + c8 * 8]) =
            *reinterpret_cast<const uint4*>(base + (size_t)row * 2304 + 768 + c8 * 8);
    }
    // stage V transposed
    for (int idx = tid; idx < LW_ * 64; idx += 256) {
        int row = idx >> 6, d = idx & 63;
        Vt[d * 232 + row] = base[(size_t)row * 2304 + 1536 + d];
    }
    // zero V^T key-padding 206..231 (NaN-safe for PV padding)
    for (int idx = tid; idx < 64 * 26; idx += 256) {
        int d = idx / 26, c = idx - d * 26;
        Vt[d * 232 + 206 + c] = (_Float16)0.0f;
    }
    __syncthreads();

    const int wv = tid >> 6, ln = tid & 63;
    const int n = ln & 15, quad = ln >> 4, qb = quad * 16;

    // rel-pos B-frags (fp32 global -> fp16), col j = ct*16+n clamped to 26
    half8 bh[2][2], bwf[2][2];
    #pragma unroll
    for (int ct = 0; ct < 2; ++ct) {
        int j = ct * 16 + n; if (j > 26) j = 26;
        #pragma unroll
        for (int kk = 0; kk < 2; ++kk) {
            const float* ph = relh + j * 64 + kk * 32 + quad * 8;
            const float* pw = relw + j * 64 + kk * 32 + quad * 8;
            half8 hf, wf;
            #pragma unroll
            for (int e = 0; e < 8; ++e) { hf[e] = (_Float16)ph[e]; wf[e] = (_Float16)pw[e]; }
            bh[ct][kk] = hf; bwf[ct][kk] = wf;
        }
    }

    // per-lane key coords per col tile
    int khv[13], kwv[13];
    #pragma unroll
    for (int ct = 0; ct < 13; ++ct) {
        int key = ct * 16 + n;
        int k2 = key - VPT_; if (k2 < 0) k2 = 0;
        khv[ct] = k2 / WSz; kwv[ct] = k2 - khv[ct] * WSz;
    }

    _Float16* pcw = &Pc[wv][0];

    for (int rt = wv; rt < 13; rt += 4) {
        // Q A-frags from global (L1/L2 hot)
        int qrow = rt * 16 + n; if (qrow > 205) qrow = 205;
        const _Float16* qp = base + (size_t)qrow * 2304 + quad * 8;
        half8 qa0 = *reinterpret_cast<const half8*>(qp);
        half8 qa1 = *reinterpret_cast<const half8*>(qp + 32);

        // T_h, T_w frags (cols 0..26 across 2 tiles each)
        floatx4 th0 = {}, th1 = {}, tw0 = {}, tw1 = {};
        th0 = __builtin_amdgcn_mfma_f32_16x16x32_f16(qa0, bh[0][0], th0, 0, 0, 0);
        th0 = __builtin_amdgcn_mfma_f32_16x16x32_f16(qa1, bh[0][1], th0, 0, 0, 0);
        th1 = __builtin_amdgcn_mfma_f32_16x16x32_f16(qa0, bh[1][0], th1, 0, 0, 0);
        th1 = __builtin_amdgcn_mfma_f32_16x16x32_f16(qa1, bh[1][1], th1, 0, 0, 0);
        tw0 = __builtin_amdgcn_mfma_f32_16x16x32_f16(qa0, bwf[0][0], tw0, 0, 0, 0);
        tw0 = __builtin_amdgcn_mfma_f32_16x16x32_f16(qa1, bwf[0][1], tw0, 0, 0, 0);
        tw1 = __builtin_amdgcn_mfma_f32_16x16x32_f16(qa0, bwf[1][0], tw1, 0, 0, 0);
        tw1 = __builtin_amdgcn_mfma_f32_16x16x32_f16(qa1, bwf[1][1], tw1, 0, 0, 0);

        // S strip: 13 col tiles
        floatx4 s[13];
        #pragma unroll
        for (int ct = 0; ct < 13; ++ct) {
            half8 kb0 = *reinterpret_cast<const half8*>(&Ks[(ct * 16 + n) * 72 + quad * 8]);
            half8 kb1 = *reinterpret_cast<const half8*>(&Ks[(ct * 16 + n) * 72 + 32 + quad * 8]);
            floatx4 a = {};
            a = __builtin_amdgcn_mfma_f32_16x16x32_f16(qa0, kb0, a, 0, 0, 0);
            a = __builtin_amdgcn_mfma_f32_16x16x32_f16(qa1, kb1, a, 0, 0, 0);
            s[ct] = a;
        }

        // scale + rel-pos + mask
        #pragma unroll
        for (int rr = 0; rr < 4; ++rr) {
            int row = rt * 16 + quad * 4 + rr;
            bool rowok = (row >= VPT_) && (row < LW_);
            int q2 = row - VPT_; if (q2 < 0) q2 = 0;
            int qh = q2 / WSz, qw = q2 - qh * WSz;
            #pragma unroll
            for (int ct = 0; ct < 13; ++ct) {
                int key = ct * 16 + n;
                int jh = qh - khv[ct] + 13;       // in [0,26] by construction
                int jw = qw - kwv[ct] + 13;
                float a0 = __shfl(th0[rr], qb + (jh & 15));
                float a1 = __shfl(th1[rr], qb + (jh & 15));
                float b0 = __shfl(tw0[rr], qb + (jw & 15));
                float b1 = __shfl(tw1[rr], qb + (jw & 15));
                float tv = (jh < 16 ? a0 : a1) + (jw < 16 ? b0 : b1);
                float sv = s[ct][rr] * 0.125f;
                sv += (rowok && key >= VPT_ && key < LW_) ? tv : 0.0f;
                if (key >= LW_) sv = -1e30f;
                s[ct][rr] = sv;
            }
        }

        // softmax (row lives in lanes qb..qb+15, reg rr)
        float mx[4] = {-1e30f, -1e30f, -1e30f, -1e30f};
        #pragma unroll
        for (int ct = 0; ct < 13; ++ct)
            #pragma unroll
            for (int rr = 0; rr < 4; ++rr) mx[rr] = fmaxf(mx[rr], s[ct][rr]);
        #pragma unroll
        for (int rr = 0; rr < 4; ++rr)
            #pragma unroll
            for (int off = 1; off < 16; off <<= 1) mx[rr] = fmaxf(mx[rr], __shfl_xor(mx[rr], off));
        float sm[4] = {0.f, 0.f, 0.f, 0.f};
        #pragma unroll
        for (int ct = 0; ct < 13; ++ct)
            #pragma unroll
            for (int rr = 0; rr < 4; ++rr) {
                float p = __expf(s[ct][rr] - mx[rr]);
                s[ct][rr] = p; sm[rr] += p;
            }
        #pragma unroll
        for (int rr = 0; rr < 4; ++rr) {
            #pragma unroll
            for (int off = 1; off < 16; off <<= 1) sm[rr] += __shfl_xor(sm[rr], off);
            sm[rr] = 1.0f / sm[rr];
        }
        #pragma unroll
        for (int ct = 0; ct < 13; ++ct)
            #pragma unroll
            for (int rr = 0; rr < 4; ++rr) s[ct][rr] *= sm[rr];

        // PV: chunk P (32 keys) through per-wave LDS, accumulate O
        floatx4 o[4] = {};
        #pragma unroll
        for (int kt = 0; kt < 7; ++kt) {
            #pragma unroll
            for (int h2 = 0; h2 < 2; ++h2) {
                int ct = kt * 2 + h2;
                #pragma unroll
                for (int rr = 0; rr < 4; ++rr) {
                    float pv = (ct < 13) ? s[ct][rr] : 0.0f;
                    pcw[(quad * 4 + rr) * 40 + h2 * 16 + n] = (_Float16)pv;
                }
            }
            half8 pa = *reinterpret_cast<const half8*>(&pcw[n * 40 + quad * 8]);
            #pragma unroll
            for (int dt = 0; dt < 4; ++dt) {
                half8 vb = *reinterpret_cast<const half8*>(&Vt[(dt * 16 + n) * 232 + kt * 32 + quad * 8]);
                o[dt] = __builtin_amdgcn_mfma_f32_16x16x32_f16(pa, vb, o[dt], 0, 0, 0);
            }
        }

        // write O (C layout)
        #pragma unroll
        for (int dt = 0; dt < 4; ++dt)
            #pragma unroll
            for (int rr = 0; rr < 4; ++rr) {
                int row = rt * 16 + quad * 4 + rr;
                if (row < LW_)
                    attout[((size_t)(bwi * LW_ + row)) * Cc + hh * HDd + dt * 16 + n] = (_Float16)o[dt][rr];
            }
    }
}

// ---------------- x2 = x + window-reverse(proj); prompt = mean over 25 windows ----------------
__global__ __launch_bounds__(256) void build_x2_kernel(
    const float* __restrict__ x, const _Float16* __restrict__ proj, float* __restrict__ x2)
{
    int r = blockIdx.x;
    int b = r / Ll, l = r % Ll;
    int t = threadIdx.x;
    size_t srow = 0;
    bool prompt = (l < VPT_);
    if (!prompt) {
        int sidx = l - VPT_;
        int ii = sidx >> 6, jj = sidx & 63;
        srow = (size_t)(b * NWIN + (ii / WSz) * 5 + (jj / WSz)) * LW_
               + VPT_ + (ii % WSz) * WSz + (jj % WSz);
    }
    #pragma unroll
    for (int i = 0; i < 3; ++i) {
        int c = t + i * 256;
        float v;
        if (prompt) {
            float s = 0.0f;
            for (int wi = 0; wi < NWIN; ++wi)
                s += (float)proj[((size_t)(wi * Bb + b) * LW_ + l) * Cc + c];
            v = s * (1.0f / NWIN);
        } else {
            v = (float)proj[srow * Cc + c];
        }
        size_t off = (size_t)r * Cc + c;
        x2[off] = x[off] + v;
    }
}

// ---------------- launcher ----------------
extern "C" void kernel_launch(void* const* d_in, const int* in_sizes, int n_in,
                              void* d_out, int out_size, void* d_ws, size_t ws_size,
                              hipStream_t stream)
{
    const float* x     = (const float*)d_in[0];
    const float* ln1w  = (const float*)d_in[1];
    const float* ln1b  = (const float*)d_in[2];
    const float* qkvw  = (const float*)d_in[3];
    const float* qkvb  = (const float*)d_in[4];
    const float* projw = (const float*)d_in[5];
    const float* projb = (const float*)d_in[6];
    const float* relh  = (const float*)d_in[7];
    const float* relw  = (const float*)d_in[8];
    const float* ln2w  = (const float*)d_in[9];
    const float* ln2b  = (const float*)d_in[10];
    const float* w1    = (const float*)d_in[11];
    const float* b1    = (const float*)d_in[12];
    const float* w2    = (const float*)d_in[13];
    const float* b2    = (const float*)d_in[14];
    float* out = (float*)d_out;
    char* ws = (char*)d_ws;

    // workspace layout (bytes); peak ~267 MB
    _Float16* wqkv_h  = (_Float16*)(ws + 0);          // 2304*768*2   = 3,538,944
    _Float16* wproj_h = (_Float16*)(ws + 3538944);    //  768*768*2   = 1,179,648
    _Float16* w1_h    = (_Float16*)(ws + 4718592);    // 3072*768*2   = 4,718,592
    _Float16* w2_h    = (_Float16*)(ws + 9437184);    //  768*3072*2  = 4,718,592
    _Float16* tokA    = (_Float16*)(ws + 14155776);   // region A: 41200*768*2 = 63,283,200
    char* regB = ws + 77438976;
    _Float16* qkv_h  = (_Float16*)regB;               // 41200*2304*2 = 189,849,600
    _Float16* proj_h = (_Float16*)regB;               // reuse after qkv dead
    float*    x2buf  = (float*)(regB + 63283200);     // 32848*768*4  = 100,927,488
    _Float16* hbuf   = (_Float16*)regB;               // reuse after proj dead

    // 1. weights -> fp16
    f2h_kernel<<<(2304 * 768 + 255) / 256, 256, 0, stream>>>(qkvw, wqkv_h, 2304 * 768);
    f2h_kernel<<<(768 * 768 + 255) / 256, 256, 0, stream>>>(projw, wproj_h, 768 * 768);
    f2h_kernel<<<(3072 * 768 + 255) / 256, 256, 0, stream>>>(w1, w1_h, 3072 * 768);
    f2h_kernel<<<(768 * 3072 + 255) / 256, 256, 0, stream>>>(w2, w2_h, 768 * 3072);
    // 2. zero tok (padded window slots must be 0)
    hipMemsetAsync(tokA, 0, (size_t)41200 * 768 * 2, stream);
    // 3. LN1 + scatter into windows
    ln1_scatter_kernel<<<Bb * Ll, 256, 0, stream>>>(x, ln1w, ln1b, tokA);
    // 4. QKV gemm (M=41200, N=2304, K=768)
    gemm_f16<0><<<dim3(644, 36), 256, 0, stream>>>(tokA, wqkv_h, qkvb, nullptr, qkv_h, nullptr, 41200, 2304, 768);
    // 5. MFMA attention -> attout (reuses region A)
    attn_mfma_kernel<<<BW_ * NHh, 256, 0, stream>>>(qkv_h, relh, relw, tokA);
    // 6. proj gemm (M=41200, N=768, K=768)
    gemm_f16<0><<<dim3(644, 12), 256, 0, stream>>>(tokA, wproj_h, projb, nullptr, proj_h, nullptr, 41200, 768, 768);
    // 7. x2 = x + window-reverse / prompt-mean
    build_x2_kernel<<<Bb * Ll, 256, 0, stream>>>(x, proj_h, x2buf);
    // 8. LN2 -> xn2 (region A)
    ln2_kernel<<<Bb * Ll, 256, 0, stream>>>(x2buf, ln2w, ln2b, tokA);
    // 9. MLP in 4 chunks of 8212 rows
    for (int ch = 0; ch < 4; ++ch) {
        size_t r0 = (size_t)ch * 8212;
        gemm_f16<1><<<dim3(129, 48), 256, 0, stream>>>(tokA + r0 * 768, w1_h, b1, nullptr, hbuf, nullptr, 8212, 3072, 768);
        gemm_f16<2><<<dim3(129, 12), 256, 0, stream>>>(hbuf, w2_h, b2, x2buf + r0 * 768, nullptr, out + r0 * 768, 8212, 768, 3072);
    }
}

// Round 3
// 1532.652 us; speedup vs baseline: 5.3315x; 1.3803x over previous
//
#include <hip/hip_runtime.h>
#include <hip/hip_fp16.h>

// ---- problem constants ----
#define Bb 8
#define Ll 4106
#define Cc 768
#define VPT_ 10
#define WSz 14
#define NWIN 25
#define BW_ 200
#define LW_ 206
#define NHh 12
#define HDd 64

typedef _Float16 half8 __attribute__((ext_vector_type(8)));
typedef float floatx4 __attribute__((ext_vector_type(4)));

// async global->LDS, 16 B per lane, wave-uniform LDS base + lane*16
__device__ __forceinline__ void gload16(const _Float16* g, _Float16* l) {
    __builtin_amdgcn_global_load_lds(
        (const __attribute__((address_space(1))) void*)g,
        (__attribute__((address_space(3))) void*)l, 16, 0, 0);
}

// ---------------- fp32 -> fp16 convert ----------------
__global__ void f2h_kernel(const float* __restrict__ in, _Float16* __restrict__ out, int n) {
    int i = blockIdx.x * 256 + threadIdx.x;
    if (i < n) out[i] = (_Float16)in[i];
}

// ---------------- LN1 + window scatter ----------------
__global__ __launch_bounds__(256) void ln1_scatter_kernel(
    const float* __restrict__ x, const float* __restrict__ w, const float* __restrict__ bia,
    _Float16* __restrict__ tok)
{
    int r = blockIdx.x;
    int b = r / Ll, l = r % Ll;
    const float* xr = x + (size_t)r * Cc;
    int t = threadIdx.x;
    float v0 = xr[t], v1 = xr[t + 256], v2 = xr[t + 512];
    float s1 = v0 + v1 + v2;
    float s2 = v0 * v0 + v1 * v1 + v2 * v2;
    #pragma unroll
    for (int off = 32; off > 0; off >>= 1) {
        s1 += __shfl_down(s1, off);
        s2 += __shfl_down(s2, off);
    }
    __shared__ float red[8];
    int wv = t >> 6, ln = t & 63;
    if (ln == 0) { red[wv] = s1; red[4 + wv] = s2; }
    __syncthreads();
    float fs1 = red[0] + red[1] + red[2] + red[3];
    float fs2 = red[4] + red[5] + red[6] + red[7];
    float mean = fs1 * (1.0f / Cc);
    float var  = fs2 * (1.0f / Cc) - mean * mean;
    float rstd = rsqrtf(var + 1e-5f);
    float vv[3] = {v0, v1, v2};
    if (l < VPT_) {
        #pragma unroll
        for (int i = 0; i < 3; ++i) {
            int c = t + i * 256;
            _Float16 hy = (_Float16)((vv[i] - mean) * rstd * w[c] + bia[c]);
            for (int wi = 0; wi < NWIN; ++wi)
                tok[((size_t)(wi * Bb + b) * LW_ + l) * Cc + c] = hy;
        }
    } else {
        int sidx = l - VPT_;
        int ii = sidx >> 6, jj = sidx & 63;
        size_t drow = (size_t)(b * NWIN + (ii / WSz) * 5 + (jj / WSz)) * LW_
                      + VPT_ + (ii % WSz) * WSz + (jj % WSz);
        #pragma unroll
        for (int i = 0; i < 3; ++i) {
            int c = t + i * 256;
            tok[drow * Cc + c] = (_Float16)((vv[i] - mean) * rstd * w[c] + bia[c]);
        }
    }
}

// ---------------- LN2 (plain) ----------------
__global__ __launch_bounds__(256) void ln2_kernel(
    const float* __restrict__ x2, const float* __restrict__ w, const float* __restrict__ bia,
    _Float16* __restrict__ xn)
{
    int r = blockIdx.x;
    const float* xr = x2 + (size_t)r * Cc;
    int t = threadIdx.x;
    float v0 = xr[t], v1 = xr[t + 256], v2 = xr[t + 512];
    float s1 = v0 + v1 + v2;
    float s2 = v0 * v0 + v1 * v1 + v2 * v2;
    #pragma unroll
    for (int off = 32; off > 0; off >>= 1) {
        s1 += __shfl_down(s1, off);
        s2 += __shfl_down(s2, off);
    }
    __shared__ float red[8];
    int wv = t >> 6, ln = t & 63;
    if (ln == 0) { red[wv] = s1; red[4 + wv] = s2; }
    __syncthreads();
    float fs1 = red[0] + red[1] + red[2] + red[3];
    float fs2 = red[4] + red[5] + red[6] + red[7];
    float mean = fs1 * (1.0f / Cc);
    float var  = fs2 * (1.0f / Cc) - mean * mean;
    float rstd = rsqrtf(var + 1e-5f);
    float vv[3] = {v0, v1, v2};
    #pragma unroll
    for (int i = 0; i < 3; ++i) {
        int c = t + i * 256;
        xn[(size_t)r * Cc + c] = (_Float16)((vv[i] - mean) * rstd * w[c] + bia[c]);
    }
}

// ---------------- m97-style MFMA fp16 GEMM: C[M,N] = A[M,K] @ W[N,K]^T + bias ----------
// 128x128 tile, BK=32, 4 waves (2x2), each wave 64x64 (4x4 16x16x32 frags).
// Staging: global_load_lds dwordx4 into unpadded As/Bs[128][32] (conflict-free frag reads:
// each wave frag read = 1024 contiguous B). Supertile swizzle (GROUP=8) for L2 A-reuse.
// EPI 0: fp16 out, 1: gelu+fp16 out (both via LDS-transpose for full-line stores),
// 2: +addsrc -> fp32 out (direct dword stores, already 64-B segments).
// N, K must be multiples of 128/32; M arbitrary (clamped loads, guarded stores).
template <int EPI>
__global__ __launch_bounds__(256) void gemm128(
    const _Float16* __restrict__ A, const _Float16* __restrict__ W,
    const float* __restrict__ bias, const float* __restrict__ addsrc,
    _Float16* __restrict__ outH, float* __restrict__ outF,
    int M, int N, int K, int gm, int gn)
{
    __shared__ alignas(16) _Float16 As[128 * 32];
    __shared__ alignas(16) _Float16 Bs[128 * 32];

    // supertile swizzle: groups of 8 row tiles, col-fastest inside a group
    int pid = blockIdx.x;
    int width = 8 * gn;
    int gid = pid / width;
    int first = gid * 8;
    int gsz = gm - first; if (gsz > 8) gsz = 8;
    int rem = pid - gid * width;
    int pm = first + rem % gsz;
    int pn = rem / gsz;
    int row0 = pm * 128, col0 = pn * 128;

    int tid = threadIdx.x;
    int wv = tid >> 6, ln = tid & 63;
    int n = ln & 15, quad = ln >> 4;
    int wr = wv >> 1, wc = wv & 1;
    int lr = ln >> 2, lg = ln & 3;

    // staging pointers: wave w loads 16-row chunks {w, w+4} of A and B
    int ar0 = row0 + wv * 16 + lr;        if (ar0 > M - 1) ar0 = M - 1;
    int ar1 = row0 + (wv + 4) * 16 + lr;  if (ar1 > M - 1) ar1 = M - 1;
    const _Float16* Ap0 = A + (size_t)ar0 * K + lg * 8;
    const _Float16* Ap1 = A + (size_t)ar1 * K + lg * 8;
    const _Float16* Bp0 = W + (size_t)(col0 + wv * 16 + lr) * K + lg * 8;
    const _Float16* Bp1 = W + (size_t)(col0 + (wv + 4) * 16 + lr) * K + lg * 8;
    _Float16* lA0 = As + wv * 512;
    _Float16* lA1 = As + (wv + 4) * 512;
    _Float16* lB0 = Bs + wv * 512;
    _Float16* lB1 = Bs + (wv + 4) * 512;

    floatx4 acc[4][4] = {};

    for (int k0 = 0; k0 < K; k0 += 32) {
        __syncthreads();                 // previous iter's LDS reads complete
        gload16(Ap0 + k0, lA0);
        gload16(Ap1 + k0, lA1);
        gload16(Bp0 + k0, lB0);
        gload16(Bp1 + k0, lB1);
        __syncthreads();                 // drains vmcnt: staged data visible
        half8 af[4], bf[4];
        #pragma unroll
        for (int i = 0; i < 4; ++i)
            af[i] = *reinterpret_cast<const half8*>(&As[(wr * 64 + i * 16 + n) * 32 + quad * 8]);
        #pragma unroll
        for (int j = 0; j < 4; ++j)
            bf[j] = *reinterpret_cast<const half8*>(&Bs[(wc * 64 + j * 16 + n) * 32 + quad * 8]);
        #pragma unroll
        for (int i = 0; i < 4; ++i)
            #pragma unroll
            for (int j = 0; j < 4; ++j)
                acc[i][j] = __builtin_amdgcn_mfma_f32_16x16x32_f16(af[i], bf[j], acc[i][j], 0, 0, 0);
    }

    float bv[4];
    #pragma unroll
    for (int j = 0; j < 4; ++j) bv[j] = bias[col0 + wc * 64 + j * 16 + n];

    if (EPI == 2) {
        #pragma unroll
        for (int i = 0; i < 4; ++i)
            #pragma unroll
            for (int j = 0; j < 4; ++j) {
                int col = col0 + wc * 64 + j * 16 + n;
                #pragma unroll
                for (int rr = 0; rr < 4; ++rr) {
                    int row = row0 + wr * 64 + i * 16 + quad * 4 + rr;
                    if (row < M) {
                        size_t off = (size_t)row * N + col;
                        outF[off] = acc[i][j][rr] + bv[j] + addsrc[off];
                    }
                }
            }
    } else {
        __syncthreads();   // all waves done reading As/Bs; safe to reuse as transpose buffers
        _Float16* Tb = (wv < 2 ? As : Bs) + (wv & 1) * 2048;   // per-wave [16][72]
        #pragma unroll
        for (int i = 0; i < 4; ++i) {
            #pragma unroll
            for (int j = 0; j < 4; ++j)
                #pragma unroll
                for (int rr = 0; rr < 4; ++rr) {
                    float v = acc[i][j][rr] + bv[j];
                    if (EPI == 1) v = 0.5f * v * (1.0f + erff(v * 0.70710678118654752f));
                    Tb[(quad * 4 + rr) * 72 + j * 16 + n] = (_Float16)v;
                }
            __syncthreads();   // lockstep; guarantees in-wave write->read visibility too
            int row = row0 + wr * 64 + i * 16 + lr;
            if (row < M) {
                uint4 p0 = *reinterpret_cast<const uint4*>(&Tb[lr * 72 + lg * 8]);
                uint4 p1 = *reinterpret_cast<const uint4*>(&Tb[lr * 72 + 32 + lg * 8]);
                _Float16* po = outH + (size_t)row * N + col0 + wc * 64 + lg * 8;
                *reinterpret_cast<uint4*>(po) = p0;
                *reinterpret_cast<uint4*>(po + 32) = p1;
            }
        }
    }
}

// ---------------- MFMA attention: one block per (window, head), 4 waves ----------------
__global__ __launch_bounds__(256, 2) void attn_mfma_kernel(
    const _Float16* __restrict__ qkv,
    const float* __restrict__ relh, const float* __restrict__ relw,
    _Float16* __restrict__ attout)
{
    __shared__ alignas(16) _Float16 Ks[208 * 72];
    __shared__ alignas(16) _Float16 Vt[64 * 232];
    __shared__ alignas(16) _Float16 Pc[4][16 * 40];
    const int bwi = blockIdx.x / NHh, hh = blockIdx.x % NHh;
    const int tid = threadIdx.x;
    const _Float16* base = qkv + (size_t)bwi * LW_ * 2304 + hh * HDd;

    for (int idx = tid; idx < LW_ * 8; idx += 256) {
        int row = idx >> 3, c8 = idx & 7;
        *reinterpret_cast<uint4*>(&Ks[row * 72 + c8 * 8]) =
            *reinterpret_cast<const uint4*>(base + (size_t)row * 2304 + 768 + c8 * 8);
    }
    for (int idx = tid; idx < LW_ * 64; idx += 256) {
        int row = idx >> 6, d = idx & 63;
        Vt[d * 232 + row] = base[(size_t)row * 2304 + 1536 + d];
    }
    for (int idx = tid; idx < 64 * 26; idx += 256) {
        int d = idx / 26, c = idx - d * 26;
        Vt[d * 232 + 206 + c] = (_Float16)0.0f;
    }
    __syncthreads();

    const int wv = tid >> 6, ln = tid & 63;
    const int n = ln & 15, quad = ln >> 4, qb = quad * 16;

    half8 bh[2][2], bwf[2][2];
    #pragma unroll
    for (int ct = 0; ct < 2; ++ct) {
        int j = ct * 16 + n; if (j > 26) j = 26;
        #pragma unroll
        for (int kk = 0; kk < 2; ++kk) {
            const float* ph = relh + j * 64 + kk * 32 + quad * 8;
            const float* pw = relw + j * 64 + kk * 32 + quad * 8;
            half8 hf, wf;
            #pragma unroll
            for (int e = 0; e < 8; ++e) { hf[e] = (_Float16)ph[e]; wf[e] = (_Float16)pw[e]; }
            bh[ct][kk] = hf; bwf[ct][kk] = wf;
        }
    }

    int khv[13], kwv[13];
    #pragma unroll
    for (int ct = 0; ct < 13; ++ct) {
        int key = ct * 16 + n;
        int k2 = key - VPT_; if (k2 < 0) k2 = 0;
        khv[ct] = k2 / WSz; kwv[ct] = k2 - khv[ct] * WSz;
    }

    _Float16* pcw = &Pc[wv][0];

    for (int rt = wv; rt < 13; rt += 4) {
        int qrow = rt * 16 + n; if (qrow > 205) qrow = 205;
        const _Float16* qp = base + (size_t)qrow * 2304 + quad * 8;
        half8 qa0 = *reinterpret_cast<const half8*>(qp);
        half8 qa1 = *reinterpret_cast<const half8*>(qp + 32);

        floatx4 th0 = {}, th1 = {}, tw0 = {}, tw1 = {};
        th0 = __builtin_amdgcn_mfma_f32_16x16x32_f16(qa0, bh[0][0], th0, 0, 0, 0);
        th0 = __builtin_amdgcn_mfma_f32_16x16x32_f16(qa1, bh[0][1], th0, 0, 0, 0);
        th1 = __builtin_amdgcn_mfma_f32_16x16x32_f16(qa0, bh[1][0], th1, 0, 0, 0);
        th1 = __builtin_amdgcn_mfma_f32_16x16x32_f16(qa1, bh[1][1], th1, 0, 0, 0);
        tw0 = __builtin_amdgcn_mfma_f32_16x16x32_f16(qa0, bwf[0][0], tw0, 0, 0, 0);
        tw0 = __builtin_amdgcn_mfma_f32_16x16x32_f16(qa1, bwf[0][1], tw0, 0, 0, 0);
        tw1 = __builtin_amdgcn_mfma_f32_16x16x32_f16(qa0, bwf[1][0], tw1, 0, 0, 0);
        tw1 = __builtin_amdgcn_mfma_f32_16x16x32_f16(qa1, bwf[1][1], tw1, 0, 0, 0);

        floatx4 s[13];
        #pragma unroll
        for (int ct = 0; ct < 13; ++ct) {
            half8 kb0 = *reinterpret_cast<const half8*>(&Ks[(ct * 16 + n) * 72 + quad * 8]);
            half8 kb1 = *reinterpret_cast<const half8*>(&Ks[(ct * 16 + n) * 72 + 32 + quad * 8]);
            floatx4 a = {};
            a = __builtin_amdgcn_mfma_f32_16x16x32_f16(qa0, kb0, a, 0, 0, 0);
            a = __builtin_amdgcn_mfma_f32_16x16x32_f16(qa1, kb1, a, 0, 0, 0);
            s[ct] = a;
        }

        #pragma unroll
        for (int rr = 0; rr < 4; ++rr) {
            int row = rt * 16 + quad * 4 + rr;
            bool rowok = (row >= VPT_) && (row < LW_);
            int q2 = row - VPT_; if (q2 < 0) q2 = 0;
            int qh = q2 / WSz, qw = q2 - qh * WSz;
            #pragma unroll
            for (int ct = 0; ct < 13; ++ct) {
                int key = ct * 16 + n;
                int jh = qh - khv[ct] + 13;
                int jw = qw - kwv[ct] + 13;
                float a0 = __shfl(th0[rr], qb + (jh & 15));
                float a1 = __shfl(th1[rr], qb + (jh & 15));
                float b0 = __shfl(tw0[rr], qb + (jw & 15));
                float b1 = __shfl(tw1[rr], qb + (jw & 15));
                float tv = (jh < 16 ? a0 : a1) + (jw < 16 ? b0 : b1);
                float sv = s[ct][rr] * 0.125f;
                sv += (rowok && key >= VPT_ && key < LW_) ? tv : 0.0f;
                if (key >= LW_) sv = -1e30f;
                s[ct][rr] = sv;
            }
        }

        float mx[4] = {-1e30f, -1e30f, -1e30f, -1e30f};
        #pragma unroll
        for (int ct = 0; ct < 13; ++ct)
            #pragma unroll
            for (int rr = 0; rr < 4; ++rr) mx[rr] = fmaxf(mx[rr], s[ct][rr]);
        #pragma unroll
        for (int rr = 0; rr < 4; ++rr)
            #pragma unroll
            for (int off = 1; off < 16; off <<= 1) mx[rr] = fmaxf(mx[rr], __shfl_xor(mx[rr], off));
        float sm[4] = {0.f, 0.f, 0.f, 0.f};
        #pragma unroll
        for (int ct = 0; ct < 13; ++ct)
            #pragma unroll
            for (int rr = 0; rr < 4; ++rr) {
                float p = __expf(s[ct][rr] - mx[rr]);
                s[ct][rr] = p; sm[rr] += p;
            }
        #pragma unroll
        for (int rr = 0; rr < 4; ++rr) {
            #pragma unroll
            for (int off = 1; off < 16; off <<= 1) sm[rr] += __shfl_xor(sm[rr], off);
            sm[rr] = 1.0f / sm[rr];
        }
        #pragma unroll
        for (int ct = 0; ct < 13; ++ct)
            #pragma unroll
            for (int rr = 0; rr < 4; ++rr) s[ct][rr] *= sm[rr];

        floatx4 o[4] = {};
        #pragma unroll
        for (int kt = 0; kt < 7; ++kt) {
            #pragma unroll
            for (int h2 = 0; h2 < 2; ++h2) {
                int ct = kt * 2 + h2;
                #pragma unroll
                for (int rr = 0; rr < 4; ++rr) {
                    float pv = (ct < 13) ? s[ct][rr] : 0.0f;
                    pcw[(quad * 4 + rr) * 40 + h2 * 16 + n] = (_Float16)pv;
                }
            }
            half8 pa = *reinterpret_cast<const half8*>(&pcw[n * 40 + quad * 8]);
            #pragma unroll
            for (int dt = 0; dt < 4; ++dt) {
                half8 vb = *reinterpret_cast<const half8*>(&Vt[(dt * 16 + n) * 232 + kt * 32 + quad * 8]);
                o[dt] = __builtin_amdgcn_mfma_f32_16x16x32_f16(pa, vb, o[dt], 0, 0, 0);
            }
        }

        #pragma unroll
        for (int dt = 0; dt < 4; ++dt)
            #pragma unroll
            for (int rr = 0; rr < 4; ++rr) {
                int row = rt * 16 + quad * 4 + rr;
                if (row < LW_)
                    attout[((size_t)(bwi * LW_ + row)) * Cc + hh * HDd + dt * 16 + n] = (_Float16)o[dt][rr];
            }
    }
}

// ---------------- x2 = x + window-reverse(proj); prompt = mean over 25 windows ----------------
__global__ __launch_bounds__(256) void build_x2_kernel(
    const float* __restrict__ x, const _Float16* __restrict__ proj, float* __restrict__ x2)
{
    int r = blockIdx.x;
    int b = r / Ll, l = r % Ll;
    int t = threadIdx.x;
    size_t srow = 0;
    bool prompt = (l < VPT_);
    if (!prompt) {
        int sidx = l - VPT_;
        int ii = sidx >> 6, jj = sidx & 63;
        srow = (size_t)(b * NWIN + (ii / WSz) * 5 + (jj / WSz)) * LW_
               + VPT_ + (ii % WSz) * WSz + (jj % WSz);
    }
    #pragma unroll
    for (int i = 0; i < 3; ++i) {
        int c = t + i * 256;
        float v;
        if (prompt) {
            float s = 0.0f;
            for (int wi = 0; wi < NWIN; ++wi)
                s += (float)proj[((size_t)(wi * Bb + b) * LW_ + l) * Cc + c];
            v = s * (1.0f / NWIN);
        } else {
            v = (float)proj[srow * Cc + c];
        }
        size_t off = (size_t)r * Cc + c;
        x2[off] = x[off] + v;
    }
}

// ---------------- launcher ----------------
extern "C" void kernel_launch(void* const* d_in, const int* in_sizes, int n_in,
                              void* d_out, int out_size, void* d_ws, size_t ws_size,
                              hipStream_t stream)
{
    const float* x     = (const float*)d_in[0];
    const float* ln1w  = (const float*)d_in[1];
    const float* ln1b  = (const float*)d_in[2];
    const float* qkvw  = (const float*)d_in[3];
    const float* qkvb  = (const float*)d_in[4];
    const float* projw = (const float*)d_in[5];
    const float* projb = (const float*)d_in[6];
    const float* relh  = (const float*)d_in[7];
    const float* relw  = (const float*)d_in[8];
    const float* ln2w  = (const float*)d_in[9];
    const float* ln2b  = (const float*)d_in[10];
    const float* w1    = (const float*)d_in[11];
    const float* b1    = (const float*)d_in[12];
    const float* w2    = (const float*)d_in[13];
    const float* b2    = (const float*)d_in[14];
    float* out = (float*)d_out;
    char* ws = (char*)d_ws;

    // workspace layout (bytes); peak ~267 MB
    _Float16* wqkv_h  = (_Float16*)(ws + 0);          // 2304*768*2   = 3,538,944
    _Float16* wproj_h = (_Float16*)(ws + 3538944);    //  768*768*2   = 1,179,648
    _Float16* w1_h    = (_Float16*)(ws + 4718592);    // 3072*768*2   = 4,718,592
    _Float16* w2_h    = (_Float16*)(ws + 9437184);    //  768*3072*2  = 4,718,592
    _Float16* tokA    = (_Float16*)(ws + 14155776);   // region A: 41200*768*2 = 63,283,200
    char* regB = ws + 77438976;
    _Float16* qkv_h  = (_Float16*)regB;               // 41200*2304*2 = 189,849,600
    _Float16* proj_h = (_Float16*)regB;               // reuse after qkv dead
    float*    x2buf  = (float*)(regB + 63283200);     // 32848*768*4  = 100,927,488
    _Float16* hbuf   = (_Float16*)regB;               // reuse after proj dead

    // 1. weights -> fp16
    f2h_kernel<<<(2304 * 768 + 255) / 256, 256, 0, stream>>>(qkvw, wqkv_h, 2304 * 768);
    f2h_kernel<<<(768 * 768 + 255) / 256, 256, 0, stream>>>(projw, wproj_h, 768 * 768);
    f2h_kernel<<<(3072 * 768 + 255) / 256, 256, 0, stream>>>(w1, w1_h, 3072 * 768);
    f2h_kernel<<<(768 * 3072 + 255) / 256, 256, 0, stream>>>(w2, w2_h, 768 * 3072);
    // 2. zero tok (padded window slots must be 0)
    hipMemsetAsync(tokA, 0, (size_t)41200 * 768 * 2, stream);
    // 3. LN1 + scatter into windows
    ln1_scatter_kernel<<<Bb * Ll, 256, 0, stream>>>(x, ln1w, ln1b, tokA);
    // 4. QKV gemm (M=41200, N=2304, K=768), grid 322x18
    gemm128<0><<<322 * 18, 256, 0, stream>>>(tokA, wqkv_h, qkvb, nullptr, qkv_h, nullptr,
                                             41200, 2304, 768, 322, 18);
    // 5. MFMA attention -> attout (reuses region A)
    attn_mfma_kernel<<<BW_ * NHh, 256, 0, stream>>>(qkv_h, relh, relw, tokA);
    // 6. proj gemm (M=41200, N=768, K=768), grid 322x6
    gemm128<0><<<322 * 6, 256, 0, stream>>>(tokA, wproj_h, projb, nullptr, proj_h, nullptr,
                                            41200, 768, 768, 322, 6);
    // 7. x2 = x + window-reverse / prompt-mean
    build_x2_kernel<<<Bb * Ll, 256, 0, stream>>>(x, proj_h, x2buf);
    // 8. LN2 -> xn2 (region A)
    ln2_kernel<<<Bb * Ll, 256, 0, stream>>>(x2buf, ln2w, ln2b, tokA);
    // 9. MLP in 4 chunks of 8212 rows
    for (int ch = 0; ch < 4; ++ch) {
        size_t r0 = (size_t)ch * 8212;
        gemm128<1><<<65 * 24, 256, 0, stream>>>(tokA + r0 * 768, w1_h, b1, nullptr, hbuf, nullptr,
                                                8212, 3072, 768, 65, 24);
        gemm128<2><<<65 * 6, 256, 0, stream>>>(hbuf, w2_h, b2, x2buf + r0 * 768, nullptr, out + r0 * 768,
                                               8212, 768, 3072, 65, 6);
    }
}

// Round 4
// 1461.593 us; speedup vs baseline: 5.5907x; 1.0486x over previous
//
#include <hip/hip_runtime.h>
#include <hip/hip_fp16.h>

// ---- problem constants ----
#define Bb 8
#define Ll 4106
#define Cc 768
#define VPT_ 10
#define WSz 14
#define NWIN 25
#define BW_ 200
#define LW_ 206
#define NHh 12
#define HDd 64

typedef _Float16 half8 __attribute__((ext_vector_type(8)));
typedef float floatx4 __attribute__((ext_vector_type(4)));

// async global->LDS, 16 B per lane, wave-uniform LDS base + lane*16
__device__ __forceinline__ void gload16(const _Float16* g, _Float16* l) {
    __builtin_amdgcn_global_load_lds(
        (const __attribute__((address_space(1))) void*)g,
        (__attribute__((address_space(3))) void*)l, 16, 0, 0);
}

// ---------------- fp32 -> fp16 convert ----------------
__global__ void f2h_kernel(const float* __restrict__ in, _Float16* __restrict__ out, int n) {
    int i = blockIdx.x * 256 + threadIdx.x;
    if (i < n) out[i] = (_Float16)in[i];
}

// ---------------- LN1 + window scatter ----------------
__global__ __launch_bounds__(256) void ln1_scatter_kernel(
    const float* __restrict__ x, const float* __restrict__ w, const float* __restrict__ bia,
    _Float16* __restrict__ tok)
{
    int r = blockIdx.x;
    int b = r / Ll, l = r % Ll;
    const float* xr = x + (size_t)r * Cc;
    int t = threadIdx.x;
    float v0 = xr[t], v1 = xr[t + 256], v2 = xr[t + 512];
    float s1 = v0 + v1 + v2;
    float s2 = v0 * v0 + v1 * v1 + v2 * v2;
    #pragma unroll
    for (int off = 32; off > 0; off >>= 1) {
        s1 += __shfl_down(s1, off);
        s2 += __shfl_down(s2, off);
    }
    __shared__ float red[8];
    int wv = t >> 6, ln = t & 63;
    if (ln == 0) { red[wv] = s1; red[4 + wv] = s2; }
    __syncthreads();
    float fs1 = red[0] + red[1] + red[2] + red[3];
    float fs2 = red[4] + red[5] + red[6] + red[7];
    float mean = fs1 * (1.0f / Cc);
    float var  = fs2 * (1.0f / Cc) - mean * mean;
    float rstd = rsqrtf(var + 1e-5f);
    float vv[3] = {v0, v1, v2};
    if (l < VPT_) {
        #pragma unroll
        for (int i = 0; i < 3; ++i) {
            int c = t + i * 256;
            _Float16 hy = (_Float16)((vv[i] - mean) * rstd * w[c] + bia[c]);
            for (int wi = 0; wi < NWIN; ++wi)
                tok[((size_t)(wi * Bb + b) * LW_ + l) * Cc + c] = hy;
        }
    } else {
        int sidx = l - VPT_;
        int ii = sidx >> 6, jj = sidx & 63;
        size_t drow = (size_t)(b * NWIN + (ii / WSz) * 5 + (jj / WSz)) * LW_
                      + VPT_ + (ii % WSz) * WSz + (jj % WSz);
        #pragma unroll
        for (int i = 0; i < 3; ++i) {
            int c = t + i * 256;
            tok[drow * Cc + c] = (_Float16)((vv[i] - mean) * rstd * w[c] + bia[c]);
        }
    }
}

// ---------------- LN2 (reads fp16 x2) ----------------
__global__ __launch_bounds__(256) void ln2_kernel(
    const _Float16* __restrict__ x2, const float* __restrict__ w, const float* __restrict__ bia,
    _Float16* __restrict__ xn)
{
    int r = blockIdx.x;
    const _Float16* xr = x2 + (size_t)r * Cc;
    int t = threadIdx.x;
    float v0 = (float)xr[t], v1 = (float)xr[t + 256], v2 = (float)xr[t + 512];
    float s1 = v0 + v1 + v2;
    float s2 = v0 * v0 + v1 * v1 + v2 * v2;
    #pragma unroll
    for (int off = 32; off > 0; off >>= 1) {
        s1 += __shfl_down(s1, off);
        s2 += __shfl_down(s2, off);
    }
    __shared__ float red[8];
    int wv = t >> 6, ln = t & 63;
    if (ln == 0) { red[wv] = s1; red[4 + wv] = s2; }
    __syncthreads();
    float fs1 = red[0] + red[1] + red[2] + red[3];
    float fs2 = red[4] + red[5] + red[6] + red[7];
    float mean = fs1 * (1.0f / Cc);
    float var  = fs2 * (1.0f / Cc) - mean * mean;
    float rstd = rsqrtf(var + 1e-5f);
    float vv[3] = {v0, v1, v2};
    #pragma unroll
    for (int i = 0; i < 3; ++i) {
        int c = t + i * 256;
        xn[(size_t)r * Cc + c] = (_Float16)((vv[i] - mean) * rstd * w[c] + bia[c]);
    }
}

// ---------------- m97-style MFMA fp16 GEMM: C[M,N] = A[M,K] @ W[N,K]^T + bias ----------
// 128x128 tile, BK=32, 4 waves (2x2), each wave 64x64 (4x4 16x16x32 frags).
// global_load_lds dwordx4 staging; XOR-swizzled K-chunks (swizzle applied on the GLOBAL
// source address since LDS dest is forced to base+lane*16): physical chunk p of row r
// holds logical chunk p ^ ((r>>1)&3). Frag ds_read_b128 then maps 16 consecutive lanes
// onto all 8 distinct 4-bank groups -> conflict-free (2 lanes/group).
// EPI 0: fp16 out, 1: gelu+fp16 out (LDS-transpose stores), 2: +addsrc(fp16) -> fp32 out.
template <int EPI>
__global__ __launch_bounds__(256) void gemm128(
    const _Float16* __restrict__ A, const _Float16* __restrict__ W,
    const float* __restrict__ bias, const _Float16* __restrict__ addsrc,
    _Float16* __restrict__ outH, float* __restrict__ outF,
    int M, int N, int K, int gm, int gn)
{
    __shared__ alignas(16) _Float16 As[128 * 32];
    __shared__ alignas(16) _Float16 Bs[128 * 32];

    // supertile swizzle: groups of 8 row tiles, row-fastest inside a group
    int pid = blockIdx.x;
    int width = 8 * gn;
    int gid = pid / width;
    int first = gid * 8;
    int gsz = gm - first; if (gsz > 8) gsz = 8;
    int rem = pid - gid * width;
    int pm = first + rem % gsz;
    int pn = rem / gsz;
    int row0 = pm * 128, col0 = pn * 128;

    int tid = threadIdx.x;
    int wv = tid >> 6, ln = tid & 63;
    int n = ln & 15, quad = ln >> 4;
    int wr = wv >> 1, wc = wv & 1;
    int lr = ln >> 2, lg = ln & 3;

    // staging: wave w loads 16-row chunks {w, w+4}; global chunk index XOR-swizzled
    int lsw = (lg ^ ((lr >> 1) & 3)) * 8;
    int ar0 = row0 + wv * 16 + lr;        if (ar0 > M - 1) ar0 = M - 1;
    int ar1 = row0 + (wv + 4) * 16 + lr;  if (ar1 > M - 1) ar1 = M - 1;
    const _Float16* Ap0 = A + (size_t)ar0 * K + lsw;
    const _Float16* Ap1 = A + (size_t)ar1 * K + lsw;
    const _Float16* Bp0 = W + (size_t)(col0 + wv * 16 + lr) * K + lsw;
    const _Float16* Bp1 = W + (size_t)(col0 + (wv + 4) * 16 + lr) * K + lsw;
    _Float16* lA0 = As + wv * 512;
    _Float16* lA1 = As + (wv + 4) * 512;
    _Float16* lB0 = Bs + wv * 512;
    _Float16* lB1 = Bs + (wv + 4) * 512;

    // frag-read physical chunk offset (same for A and B: depends on lane's n, quad)
    const int cq = (quad ^ ((n >> 1) & 3)) * 8;

    floatx4 acc[4][4] = {};

    for (int k0 = 0; k0 < K; k0 += 32) {
        __syncthreads();                 // previous iter's LDS reads complete
        gload16(Ap0 + k0, lA0);
        gload16(Ap1 + k0, lA1);
        gload16(Bp0 + k0, lB0);
        gload16(Bp1 + k0, lB1);
        __syncthreads();                 // drains vmcnt: staged data visible
        half8 af[4], bf[4];
        #pragma unroll
        for (int i = 0; i < 4; ++i)
            af[i] = *reinterpret_cast<const half8*>(&As[(wr * 64 + i * 16 + n) * 32 + cq]);
        #pragma unroll
        for (int j = 0; j < 4; ++j)
            bf[j] = *reinterpret_cast<const half8*>(&Bs[(wc * 64 + j * 16 + n) * 32 + cq]);
        #pragma unroll
        for (int i = 0; i < 4; ++i)
            #pragma unroll
            for (int j = 0; j < 4; ++j)
                acc[i][j] = __builtin_amdgcn_mfma_f32_16x16x32_f16(af[i], bf[j], acc[i][j], 0, 0, 0);
    }

    float bv[4];
    #pragma unroll
    for (int j = 0; j < 4; ++j) bv[j] = bias[col0 + wc * 64 + j * 16 + n];

    if (EPI == 2) {
        #pragma unroll
        for (int i = 0; i < 4; ++i)
            #pragma unroll
            for (int j = 0; j < 4; ++j) {
                int col = col0 + wc * 64 + j * 16 + n;
                #pragma unroll
                for (int rr = 0; rr < 4; ++rr) {
                    int row = row0 + wr * 64 + i * 16 + quad * 4 + rr;
                    if (row < M) {
                        size_t off = (size_t)row * N + col;
                        outF[off] = acc[i][j][rr] + bv[j] + (float)addsrc[off];
                    }
                }
            }
    } else {
        __syncthreads();   // all waves done reading As/Bs; safe to reuse as transpose buffers
        _Float16* Tb = (wv < 2 ? As : Bs) + (wv & 1) * 2048;   // per-wave [16][72]
        #pragma unroll
        for (int i = 0; i < 4; ++i) {
            #pragma unroll
            for (int j = 0; j < 4; ++j)
                #pragma unroll
                for (int rr = 0; rr < 4; ++rr) {
                    float v = acc[i][j][rr] + bv[j];
                    if (EPI == 1) v = 0.5f * v * (1.0f + erff(v * 0.70710678118654752f));
                    Tb[(quad * 4 + rr) * 72 + j * 16 + n] = (_Float16)v;
                }
            __syncthreads();   // lockstep; guarantees in-wave write->read visibility too
            int row = row0 + wr * 64 + i * 16 + lr;
            if (row < M) {
                uint4 p0 = *reinterpret_cast<const uint4*>(&Tb[lr * 72 + lg * 8]);
                uint4 p1 = *reinterpret_cast<const uint4*>(&Tb[lr * 72 + 32 + lg * 8]);
                _Float16* po = outH + (size_t)row * N + col0 + wc * 64 + lg * 8;
                *reinterpret_cast<uint4*>(po) = p0;
                *reinterpret_cast<uint4*>(po + 32) = p1;
            }
        }
    }
}

// ---------------- MFMA attention: one block per (window, head), 4 waves ----------------
__global__ __launch_bounds__(256, 2) void attn_mfma_kernel(
    const _Float16* __restrict__ qkv,
    const float* __restrict__ relh, const float* __restrict__ relw,
    _Float16* __restrict__ attout)
{
    __shared__ alignas(16) _Float16 Ks[208 * 72];
    __shared__ alignas(16) _Float16 Vt[64 * 232];
    __shared__ alignas(16) _Float16 Pc[4][16 * 40];
    const int bwi = blockIdx.x / NHh, hh = blockIdx.x % NHh;
    const int tid = threadIdx.x;
    const _Float16* base = qkv + (size_t)bwi * LW_ * 2304 + hh * HDd;

    for (int idx = tid; idx < LW_ * 8; idx += 256) {
        int row = idx >> 3, c8 = idx & 7;
        *reinterpret_cast<uint4*>(&Ks[row * 72 + c8 * 8]) =
            *reinterpret_cast<const uint4*>(base + (size_t)row * 2304 + 768 + c8 * 8);
    }
    for (int idx = tid; idx < LW_ * 64; idx += 256) {
        int row = idx >> 6, d = idx & 63;
        Vt[d * 232 + row] = base[(size_t)row * 2304 + 1536 + d];
    }
    for (int idx = tid; idx < 64 * 26; idx += 256) {
        int d = idx / 26, c = idx - d * 26;
        Vt[d * 232 + 206 + c] = (_Float16)0.0f;
    }
    __syncthreads();

    const int wv = tid >> 6, ln = tid & 63;
    const int n = ln & 15, quad = ln >> 4, qb = quad * 16;

    half8 bh[2][2], bwf[2][2];
    #pragma unroll
    for (int ct = 0; ct < 2; ++ct) {
        int j = ct * 16 + n; if (j > 26) j = 26;
        #pragma unroll
        for (int kk = 0; kk < 2; ++kk) {
            const float* ph = relh + j * 64 + kk * 32 + quad * 8;
            const float* pw = relw + j * 64 + kk * 32 + quad * 8;
            half8 hf, wf;
            #pragma unroll
            for (int e = 0; e < 8; ++e) { hf[e] = (_Float16)ph[e]; wf[e] = (_Float16)pw[e]; }
            bh[ct][kk] = hf; bwf[ct][kk] = wf;
        }
    }

    int khv[13], kwv[13];
    #pragma unroll
    for (int ct = 0; ct < 13; ++ct) {
        int key = ct * 16 + n;
        int k2 = key - VPT_; if (k2 < 0) k2 = 0;
        khv[ct] = k2 / WSz; kwv[ct] = k2 - khv[ct] * WSz;
    }

    _Float16* pcw = &Pc[wv][0];

    for (int rt = wv; rt < 13; rt += 4) {
        int qrow = rt * 16 + n; if (qrow > 205) qrow = 205;
        const _Float16* qp = base + (size_t)qrow * 2304 + quad * 8;
        half8 qa0 = *reinterpret_cast<const half8*>(qp);
        half8 qa1 = *reinterpret_cast<const half8*>(qp + 32);

        floatx4 th0 = {}, th1 = {}, tw0 = {}, tw1 = {};
        th0 = __builtin_amdgcn_mfma_f32_16x16x32_f16(qa0, bh[0][0], th0, 0, 0, 0);
        th0 = __builtin_amdgcn_mfma_f32_16x16x32_f16(qa1, bh[0][1], th0, 0, 0, 0);
        th1 = __builtin_amdgcn_mfma_f32_16x16x32_f16(qa0, bh[1][0], th1, 0, 0, 0);
        th1 = __builtin_amdgcn_mfma_f32_16x16x32_f16(qa1, bh[1][1], th1, 0, 0, 0);
        tw0 = __builtin_amdgcn_mfma_f32_16x16x32_f16(qa0, bwf[0][0], tw0, 0, 0, 0);
        tw0 = __builtin_amdgcn_mfma_f32_16x16x32_f16(qa1, bwf[0][1], tw0, 0, 0, 0);
        tw1 = __builtin_amdgcn_mfma_f32_16x16x32_f16(qa0, bwf[1][0], tw1, 0, 0, 0);
        tw1 = __builtin_amdgcn_mfma_f32_16x16x32_f16(qa1, bwf[1][1], tw1, 0, 0, 0);

        floatx4 s[13];
        #pragma unroll
        for (int ct = 0; ct < 13; ++ct) {
            half8 kb0 = *reinterpret_cast<const half8*>(&Ks[(ct * 16 + n) * 72 + quad * 8]);
            half8 kb1 = *reinterpret_cast<const half8*>(&Ks[(ct * 16 + n) * 72 + 32 + quad * 8]);
            floatx4 a = {};
            a = __builtin_amdgcn_mfma_f32_16x16x32_f16(qa0, kb0, a, 0, 0, 0);
            a = __builtin_amdgcn_mfma_f32_16x16x32_f16(qa1, kb1, a, 0, 0, 0);
            s[ct] = a;
        }

        #pragma unroll
        for (int rr = 0; rr < 4; ++rr) {
            int row = rt * 16 + quad * 4 + rr;
            bool rowok = (row >= VPT_) && (row < LW_);
            int q2 = row - VPT_; if (q2 < 0) q2 = 0;
            int qh = q2 / WSz, qw = q2 - qh * WSz;
            #pragma unroll
            for (int ct = 0; ct < 13; ++ct) {
                int key = ct * 16 + n;
                int jh = qh - khv[ct] + 13;
                int jw = qw - kwv[ct] + 13;
                float a0 = __shfl(th0[rr], qb + (jh & 15));
                float a1 = __shfl(th1[rr], qb + (jh & 15));
                float b0 = __shfl(tw0[rr], qb + (jw & 15));
                float b1 = __shfl(tw1[rr], qb + (jw & 15));
                float tv = (jh < 16 ? a0 : a1) + (jw < 16 ? b0 : b1);
                float sv = s[ct][rr] * 0.125f;
                sv += (rowok && key >= VPT_ && key < LW_) ? tv : 0.0f;
                if (key >= LW_) sv = -1e30f;
                s[ct][rr] = sv;
            }
        }

        float mx[4] = {-1e30f, -1e30f, -1e30f, -1e30f};
        #pragma unroll
        for (int ct = 0; ct < 13; ++ct)
            #pragma unroll
            for (int rr = 0; rr < 4; ++rr) mx[rr] = fmaxf(mx[rr], s[ct][rr]);
        #pragma unroll
        for (int rr = 0; rr < 4; ++rr)
            #pragma unroll
            for (int off = 1; off < 16; off <<= 1) mx[rr] = fmaxf(mx[rr], __shfl_xor(mx[rr], off));
        float sm[4] = {0.f, 0.f, 0.f, 0.f};
        #pragma unroll
        for (int ct = 0; ct < 13; ++ct)
            #pragma unroll
            for (int rr = 0; rr < 4; ++rr) {
                float p = __expf(s[ct][rr] - mx[rr]);
                s[ct][rr] = p; sm[rr] += p;
            }
        #pragma unroll
        for (int rr = 0; rr < 4; ++rr) {
            #pragma unroll
            for (int off = 1; off < 16; off <<= 1) sm[rr] += __shfl_xor(sm[rr], off);
            sm[rr] = 1.0f / sm[rr];
        }
        #pragma unroll
        for (int ct = 0; ct < 13; ++ct)
            #pragma unroll
            for (int rr = 0; rr < 4; ++rr) s[ct][rr] *= sm[rr];

        floatx4 o[4] = {};
        #pragma unroll
        for (int kt = 0; kt < 7; ++kt) {
            #pragma unroll
            for (int h2 = 0; h2 < 2; ++h2) {
                int ct = kt * 2 + h2;
                #pragma unroll
                for (int rr = 0; rr < 4; ++rr) {
                    float pv = (ct < 13) ? s[ct][rr] : 0.0f;
                    pcw[(quad * 4 + rr) * 40 + h2 * 16 + n] = (_Float16)pv;
                }
            }
            half8 pa = *reinterpret_cast<const half8*>(&pcw[n * 40 + quad * 8]);
            #pragma unroll
            for (int dt = 0; dt < 4; ++dt) {
                half8 vb = *reinterpret_cast<const half8*>(&Vt[(dt * 16 + n) * 232 + kt * 32 + quad * 8]);
                o[dt] = __builtin_amdgcn_mfma_f32_16x16x32_f16(pa, vb, o[dt], 0, 0, 0);
            }
        }

        #pragma unroll
        for (int dt = 0; dt < 4; ++dt)
            #pragma unroll
            for (int rr = 0; rr < 4; ++rr) {
                int row = rt * 16 + quad * 4 + rr;
                if (row < LW_)
                    attout[((size_t)(bwi * LW_ + row)) * Cc + hh * HDd + dt * 16 + n] = (_Float16)o[dt][rr];
            }
    }
}

// ---------------- x2 = x + window-reverse(proj); prompt = mean over 25 windows; fp16 out ----
__global__ __launch_bounds__(256) void build_x2_kernel(
    const float* __restrict__ x, const _Float16* __restrict__ proj, _Float16* __restrict__ x2)
{
    int r = blockIdx.x;
    int b = r / Ll, l = r % Ll;
    int t = threadIdx.x;
    size_t srow = 0;
    bool prompt = (l < VPT_);
    if (!prompt) {
        int sidx = l - VPT_;
        int ii = sidx >> 6, jj = sidx & 63;
        srow = (size_t)(b * NWIN + (ii / WSz) * 5 + (jj / WSz)) * LW_
               + VPT_ + (ii % WSz) * WSz + (jj % WSz);
    }
    #pragma unroll
    for (int i = 0; i < 3; ++i) {
        int c = t + i * 256;
        float v;
        if (prompt) {
            float s = 0.0f;
            for (int wi = 0; wi < NWIN; ++wi)
                s += (float)proj[((size_t)(wi * Bb + b) * LW_ + l) * Cc + c];
            v = s * (1.0f / NWIN);
        } else {
            v = (float)proj[srow * Cc + c];
        }
        size_t off = (size_t)r * Cc + c;
        x2[off] = (_Float16)(x[off] + v);
    }
}

// ---------------- launcher ----------------
extern "C" void kernel_launch(void* const* d_in, const int* in_sizes, int n_in,
                              void* d_out, int out_size, void* d_ws, size_t ws_size,
                              hipStream_t stream)
{
    const float* x     = (const float*)d_in[0];
    const float* ln1w  = (const float*)d_in[1];
    const float* ln1b  = (const float*)d_in[2];
    const float* qkvw  = (const float*)d_in[3];
    const float* qkvb  = (const float*)d_in[4];
    const float* projw = (const float*)d_in[5];
    const float* projb = (const float*)d_in[6];
    const float* relh  = (const float*)d_in[7];
    const float* relw  = (const float*)d_in[8];
    const float* ln2w  = (const float*)d_in[9];
    const float* ln2b  = (const float*)d_in[10];
    const float* w1    = (const float*)d_in[11];
    const float* b1    = (const float*)d_in[12];
    const float* w2    = (const float*)d_in[13];
    const float* b2    = (const float*)d_in[14];
    float* out = (float*)d_out;
    char* ws = (char*)d_ws;

    // workspace layout (bytes); peak 267.3 MB (during QKV gemm)
    _Float16* wqkv_h  = (_Float16*)(ws + 0);          // 2304*768*2   = 3,538,944
    _Float16* wproj_h = (_Float16*)(ws + 3538944);    //  768*768*2   = 1,179,648
    _Float16* w1_h    = (_Float16*)(ws + 4718592);    // 3072*768*2   = 4,718,592
    _Float16* w2_h    = (_Float16*)(ws + 9437184);    //  768*3072*2  = 4,718,592
    _Float16* tokA    = (_Float16*)(ws + 14155776);   // region A: 41200*768*2 = 63,283,200
    char* regB = ws + 77438976;
    _Float16* qkv_h  = (_Float16*)regB;               // 41200*2304*2 = 189,849,600 (dies after attn)
    _Float16* proj_h = (_Float16*)regB;               // 63,283,200 (dies after build_x2)
    _Float16* hbuf   = (_Float16*)regB;               // 16424*3072*2 = 100,909,056 (MLP phase)
    _Float16* x2h    = (_Float16*)(regB + 100909056); // 32848*768*2  = 50,454,528

    // 1. weights -> fp16
    f2h_kernel<<<(2304 * 768 + 255) / 256, 256, 0, stream>>>(qkvw, wqkv_h, 2304 * 768);
    f2h_kernel<<<(768 * 768 + 255) / 256, 256, 0, stream>>>(projw, wproj_h, 768 * 768);
    f2h_kernel<<<(3072 * 768 + 255) / 256, 256, 0, stream>>>(w1, w1_h, 3072 * 768);
    f2h_kernel<<<(768 * 3072 + 255) / 256, 256, 0, stream>>>(w2, w2_h, 768 * 3072);
    // 2. zero tok (padded window slots must be 0)
    hipMemsetAsync(tokA, 0, (size_t)41200 * 768 * 2, stream);
    // 3. LN1 + scatter into windows
    ln1_scatter_kernel<<<Bb * Ll, 256, 0, stream>>>(x, ln1w, ln1b, tokA);
    // 4. QKV gemm (M=41200, N=2304, K=768), grid 322x18
    gemm128<0><<<322 * 18, 256, 0, stream>>>(tokA, wqkv_h, qkvb, nullptr, qkv_h, nullptr,
                                             41200, 2304, 768, 322, 18);
    // 5. MFMA attention -> attout (reuses region A)
    attn_mfma_kernel<<<BW_ * NHh, 256, 0, stream>>>(qkv_h, relh, relw, tokA);
    // 6. proj gemm (M=41200, N=768, K=768), grid 322x6
    gemm128<0><<<322 * 6, 256, 0, stream>>>(tokA, wproj_h, projb, nullptr, proj_h, nullptr,
                                            41200, 768, 768, 322, 6);
    // 7. x2 = x + window-reverse / prompt-mean (fp16)
    build_x2_kernel<<<Bb * Ll, 256, 0, stream>>>(x, proj_h, x2h);
    // 8. LN2 -> xn2 (region A)
    ln2_kernel<<<Bb * Ll, 256, 0, stream>>>(x2h, ln2w, ln2b, tokA);
    // 9. MLP in 2 chunks of 16424 rows (hbuf reuses regB head; proj dead by now)
    for (int ch = 0; ch < 2; ++ch) {
        size_t r0 = (size_t)ch * 16424;
        gemm128<1><<<129 * 24, 256, 0, stream>>>(tokA + r0 * 768, w1_h, b1, nullptr, hbuf, nullptr,
                                                 16424, 3072, 768, 129, 24);
        gemm128<2><<<129 * 6, 256, 0, stream>>>(hbuf, w2_h, b2, x2h + r0 * 768, nullptr, out + r0 * 768,
                                                16424, 768, 3072, 129, 6);
    }
}